// Round 7
// baseline (514.826 us; speedup 1.0000x reference)
//
#include <hip/hip_runtime.h>
#include <hip/hip_bf16.h>

// B=32, S=577, H=1024, NH=16, DH=64. fp32 inputs / fp32 OUTPUT.
// Round 13: qkv 8-phase FIXED. R12's port had (a) no read->MFMA barrier
// split (the m196 lever), (b) [256][32] 64B-row layout = 8-way bank
// conflict on every A/B fragment read (LDS == critical path). Now: per
// phase {reads ∥ stage -> s_barrier -> setprio(1) 16 MFMA}, phases keyed
// (K-half, j-pair); vmcnt(4) twice per tile (counted, never 0 in loop);
// XOR chunk swizzle quad^(l16&3) on reads with inverse-swizzled staging
// source cols (involution, both-sides); tail = dead-write stages keep
// vmcnt counts uniform. Epilogues/staging pointers = R12 (verified).
// out_gemm R9 1-phase (known-good), flash_attn R11 (unchanged).

typedef __bf16 bf16_t;
typedef __bf16 bf16x8 __attribute__((ext_vector_type(8)));
typedef __bf16 bf16x4 __attribute__((ext_vector_type(4)));
typedef float f32x4 __attribute__((ext_vector_type(4)));

#define B_   32
#define S_   577
#define SP   608
#define H_   1024
#define NH_  16
#define DH_  64
#define M_   (B_ * S_)    // 18464

typedef __attribute__((address_space(3))) unsigned int lds_u32;
typedef const __attribute__((address_space(1))) unsigned int glb_u32;
#define STAGE16(gp, lp) __builtin_amdgcn_global_load_lds((glb_u32*)(gp), (lds_u32*)(lp), 16, 0, 0)
#define MFMA_BF16 __builtin_amdgcn_mfma_f32_16x16x32_bf16

__device__ __forceinline__ bf16x8 load8(const bf16_t* p) {
    return *reinterpret_cast<const bf16x8*>(p);
}
__device__ __forceinline__ bf16x8 load8f(const float* p) {
    f32x4 a = *reinterpret_cast<const f32x4*>(p);
    f32x4 b = *reinterpret_cast<const f32x4*>(p + 4);
    bf16x8 r;
    r[0] = (bf16_t)a[0]; r[1] = (bf16_t)a[1]; r[2] = (bf16_t)a[2]; r[3] = (bf16_t)a[3];
    r[4] = (bf16_t)b[0]; r[5] = (bf16_t)b[1]; r[6] = (bf16_t)b[2]; r[7] = (bf16_t)b[3];
    return r;
}

// ---------------- fp32 -> bf16 convert ----------------
__global__ __launch_bounds__(256) void cvt_f32_bf16(const float* __restrict__ src,
                                                    bf16_t* __restrict__ dst, int n8)
{
    int i = blockIdx.x * blockDim.x + threadIdx.x;
    const int stride = gridDim.x * blockDim.x;
    for (; i < n8; i += stride)
        *reinterpret_cast<bf16x8*>(dst + (size_t)i * 8) = load8f(src + (size_t)i * 8);
}

// all four weights in one launch; dsts are contiguous (Wqb..Wob in ws).
__global__ __launch_bounds__(256) void cvt_w4(
    const float* __restrict__ s0, const float* __restrict__ s1,
    const float* __restrict__ s2, const float* __restrict__ s3,
    bf16_t* __restrict__ dst)
{
    const int i = blockIdx.x * blockDim.x + threadIdx.x;   // 0..524287 (4*131072)
    const int which = i >> 17;                             // uniform per block
    const int off = i & ((1 << 17) - 1);
    const float* s = (which == 0) ? s0 : (which == 1) ? s1 : (which == 2) ? s2 : s3;
    *reinterpret_cast<bf16x8*>(dst + (size_t)i * 8) = load8f(s + (size_t)off * 8);
}

// ======== 256^2 8-phase qkv_gemm (fixed schedule + swizzle) ========
// LDS: A region (buf,kh) at ((buf*2+kh)*8192) el, B at +32768. Region =
// [256 rows][32 k-cols] row-major, 16KB. Chunk swizzle: logical 16B-chunk
// q at row r lives at phys chunk q^(r&3). Stage dest is LINEAR (DMA);
// source cols pre-swizzled (involution => read(q^(r&3)) returns logical q).
#define AR(buf, kh) (((buf) * 2 + (kh)) * 8192)
#define BR(buf, kh) (32768 + ((buf) * 2 + (kh)) * 8192)

#define STG_A(buf, kh, T)                                                        \
    do {                                                                         \
        STAGE16(pA0 + (T) * 64 + (kh) * 32, smem + AR(buf, kh) + w * 512);       \
        STAGE16(pA1 + (T) * 64 + (kh) * 32, smem + AR(buf, kh) + 4096 + w * 512);\
    } while (0)
#define STG_B(buf, kh, T)                                                        \
    do {                                                                         \
        STAGE16(pB0 + (T) * 64 + (kh) * 32, smem + BR(buf, kh) + w * 512);       \
        STAGE16(pB1 + (T) * 64 + (kh) * 32, smem + BR(buf, kh) + 4096 + w * 512);\
    } while (0)

// fragment reads (rdsw = (quad ^ (l16&3))*8, rows ≡ l16 mod 4)
#define RD_A(buf, kh)                                                            \
    do { _Pragma("unroll")                                                       \
        for (int i = 0; i < 8; ++i)                                              \
            af[i] = load8(smem + AR(buf, kh) + (wr * 128 + i * 16 + l16) * 32 + rdsw); \
    } while (0)
#define RD_B(buf, kh, j)                                                         \
    bfv[j] = load8(smem + BR(buf, kh) + (wc * 64 + (j) * 16 + l16) * 32 + rdsw)

// 16-MFMA cluster for j-pair (jj, jj+1)
#define MM(jj, SWAP)                                                             \
    do {                                                                         \
        __builtin_amdgcn_s_setprio(1);                                           \
        _Pragma("unroll")                                                        \
        for (int i = 0; i < 8; ++i) {                                            \
            acc[i][jj]     = (SWAP) ? MFMA_BF16(bfv[jj], af[i], acc[i][jj], 0, 0, 0)     \
                                    : MFMA_BF16(af[i], bfv[jj], acc[i][jj], 0, 0, 0);    \
            acc[i][jj + 1] = (SWAP) ? MFMA_BF16(bfv[jj + 1], af[i], acc[i][jj + 1], 0, 0, 0) \
                                    : MFMA_BF16(af[i], bfv[jj + 1], acc[i][jj + 1], 0, 0, 0);\
        }                                                                        \
        __builtin_amdgcn_s_setprio(0);                                           \
    } while (0)

#define VMB4 do { asm volatile("s_waitcnt vmcnt(4)" ::: "memory");               \
                  __builtin_amdgcn_s_barrier(); } while (0)
#define BAR  __builtin_amdgcn_s_barrier()

// One K-tile (BK=64) = 4 phases. CUR = buffer literal; T = tile idx;
// TS = clamped stage-target tile (dead-write at tail, counts uniform).
// vmcnt(4) boundary: retires this tile's kh0 stages (issued 2 tiles of
// phases earlier); mid: retires kh1. 2 loads/stage x 4 in flight max = 8.
#define TILE(CUR, T, TS, SWAP)                                                   \
    do {                                                                         \
        VMB4;                                                                    \
        RD_A(CUR, 0); RD_B(CUR, 0, 0); RD_B(CUR, 0, 1);                          \
        STG_A(CUR ^ 1, 0, TS);                                                   \
        BAR; MM(0, SWAP);                                                        \
        RD_B(CUR, 0, 2); RD_B(CUR, 0, 3);                                        \
        STG_B(CUR ^ 1, 0, TS);                                                   \
        BAR; MM(2, SWAP);                                                        \
        VMB4;                                                                    \
        RD_A(CUR, 1); RD_B(CUR, 1, 0); RD_B(CUR, 1, 1);                          \
        STG_A(CUR ^ 1, 1, TS);                                                   \
        BAR; MM(0, SWAP);                                                        \
        RD_B(CUR, 1, 2); RD_B(CUR, 1, 3);                                        \
        STG_B(CUR ^ 1, 1, TS);                                                   \
        BAR; MM(2, SWAP);                                                        \
    } while (0)

#define QKV_MAIN(SWAP)                                                           \
    STG_A(0, 0, 0); STG_B(0, 0, 0); STG_A(0, 1, 0); STG_B(0, 1, 0);              \
    for (int it = 0; it < 8; ++it) {                                             \
        const int t0 = 2 * it, t1 = 2 * it + 1;                                  \
        const int s0 = t1, s1 = (t1 + 1 < 16) ? t1 + 1 : 15;                     \
        TILE(0, t0, s0, SWAP);                                                   \
        TILE(1, t1, s1, SWAP);                                                   \
    }                                                                            \
    asm volatile("s_waitcnt vmcnt(0)" ::: "memory");  /* drain before exit */

// grid 876 = 73 m-tiles x 12 n-tiles, 512 threads (8 waves as 2x4).
__global__ __launch_bounds__(512, 2) void qkv_gemm(
    const bf16_t* __restrict__ Xb,
    const bf16_t* __restrict__ Wqb, const bf16_t* __restrict__ Wkb, const bf16_t* __restrict__ Wvb,
    const float* __restrict__ bq, const float* __restrict__ bk, const float* __restrict__ bv,
    bf16_t* __restrict__ Qb, bf16_t* __restrict__ Kb, bf16_t* __restrict__ VTb)
{
    __shared__ bf16_t smem[65536];          // 128 KiB
    const int tid  = threadIdx.x;
    const int w    = tid >> 6, lane = tid & 63;
    const int quad = lane >> 4, l16 = lane & 15;
    const int wr = w >> 2, wc = w & 3;      // 2x4 wave grid; wave tile 128x64
    const int rdsw = (quad ^ (l16 & 3)) * 8;

    // bijective XCD swizzle (876 = 8*109 + 4, m204) + 4-m-tile slabs n-fast
    const int orig = blockIdx.x;
    const int xcd = orig & 7, lin = orig >> 3;
    const int work = (xcd < 4 ? xcd * 110 : 440 + (xcd - 4) * 109) + lin;
    int mt, nt;
    if (work < 864) { const int slab = work / 48, rem = work - slab * 48;
                      nt = rem >> 2; mt = slab * 4 + (rem & 3); }
    else            { nt = work - 864; mt = 72; }
    const int m0 = mt * 256, n0 = nt * 256;

    const int which = n0 >> 10;             // 256-tile never straddles a weight
    const int nrel0 = n0 & 1023;
    const bf16_t* Wb   = (which == 0) ? Wqb : (which == 1) ? Wkb : Wvb;
    const float*  bias = (which == 0) ? bq  : (which == 1) ? bk  : bv;
    const float   oscale = (which == 0) ? 0.125f : 1.0f;

    // stage source pointers, cols pre-swizzled: thread t covers phys chunk
    // (t&3) of rows (t>>2) and 128+(t>>2); logical col = ((t&3)^((t>>2)&3))*8.
    const int srow = tid >> 2;
    const int scol = (((tid & 3) ^ ((tid >> 2) & 3))) * 8;
    int ga0 = m0 + srow;       if (ga0 > M_ - 1) ga0 = M_ - 1;
    int ga1 = m0 + 128 + srow; if (ga1 > M_ - 1) ga1 = M_ - 1;
    const bf16_t* pA0 = Xb + (size_t)ga0 * H_ + scol;
    const bf16_t* pA1 = Xb + (size_t)ga1 * H_ + scol;
    const bf16_t* pB0 = Wb + (size_t)(nrel0 + srow) * H_ + scol;
    const bf16_t* pB1 = Wb + (size_t)(nrel0 + 128 + srow) * H_ + scol;

    bf16x8 af[8], bfv[4];
    f32x4 acc[8][4] = {};

    if (which != 2) {
        QKV_MAIN(1)
        // swapped: m = m0+wr*128+i*16+l16 ; n-run = nrel0+wc*64+j*16+quad*4+r
        bf16_t* QKout = (which == 0) ? Qb : Kb;
#pragma unroll
        for (int j = 0; j < 4; ++j) {
            const int nrelj = nrel0 + wc * 64 + j * 16 + quad * 4;
            const int h = nrelj >> 6, d0 = nrelj & 63;
            const f32x4 b4 = *reinterpret_cast<const f32x4*>(&bias[nrelj]);
#pragma unroll
            for (int i = 0; i < 8; ++i) {
                const int m = m0 + wr * 128 + i * 16 + l16;
                if (m >= M_) continue;
                const int b = m / S_, s = m - b * S_;
                const int bh = b * NH_ + h;
                bf16x4 pk;
#pragma unroll
                for (int r = 0; r < 4; ++r) pk[r] = (bf16_t)((acc[i][j][r] + b4[r]) * oscale);
                *reinterpret_cast<bf16x4*>(QKout + ((size_t)bh * S_ + s) * DH_ + d0) = pk;
            }
        }
    } else {
        QKV_MAIN(0)
        // normal: d from l16 ; s-run = m0+wr*128+i*16+quad*4+r
#pragma unroll
        for (int j = 0; j < 4; ++j) {
            const int nrelj = nrel0 + wc * 64 + j * 16 + l16;
            const int h = nrelj >> 6, d = nrelj & 63;
            const float bv_ = bias[nrelj];
#pragma unroll
            for (int i = 0; i < 8; ++i) {
                const int m = m0 + wr * 128 + i * 16 + quad * 4;
                const int b = m / S_, s = m - b * S_;
                if (m + 3 < M_ && s <= S_ - 4) {   // 4-run stays in one batch row
                    bf16x4 pk;
#pragma unroll
                    for (int r = 0; r < 4; ++r) pk[r] = (bf16_t)(acc[i][j][r] + bv_);
                    *reinterpret_cast<bf16x4*>(VTb + ((size_t)(b * NH_ + h) * DH_ + d) * SP + s) = pk;
                } else {
#pragma unroll
                    for (int r = 0; r < 4; ++r) {
                        const int mm = m + r;
                        if (mm >= M_) continue;
                        const int bb = mm / S_, ss = mm - bb * S_;
                        VTb[((size_t)(bb * NH_ + h) * DH_ + d) * SP + ss] = (bf16_t)(acc[i][j][r] + bv_);
                    }
                }
            }
        }
    }
}

// ---------------- flash attention, zero-shuffle + setprio (R11) ----------------
__global__ __launch_bounds__(256, 3) void flash_attn(
    const bf16_t* __restrict__ Qb, const bf16_t* __restrict__ Kb,
    const bf16_t* __restrict__ VTb, const float* __restrict__ maskp,
    bf16_t* __restrict__ Ctx)
{
    __shared__ __align__(16) float smask[SP];       // 2432B, zero-padded tail
    const int tid  = threadIdx.x;
    const int w    = tid >> 6, lane = tid & 63;
    const int quad = lane >> 4, l16 = lane & 15;

    const int bid  = blockIdx.x;
    const int work = (bid & 7) * 320 + (bid >> 3);  // bijective (2560%8==0)
    const int bh   = work / 5;
    const int qx   = work - bh * 5;
    const int b    = bh >> 4, h = bh & 15;

    for (int i = tid; i < SP; i += 256)
        smask[i] = (i < S_) ? maskp[b * S_ + i] : 0.f;
    __syncthreads();

    int idx = qx * 4 + w; if (idx > 18) idx = 18;   // dup work, same values
    const int q0 = idx * 32;

    const bf16_t* Qh = Qb  + (size_t)bh * S_ * DH_;
    const bf16_t* Kh = Kb  + (size_t)bh * S_ * DH_;
    const bf16_t* Vh = VTb + (size_t)bh * DH_ * SP;

    int rqA = q0 + l16;      if (rqA > S_ - 1) rqA = S_ - 1;
    int rqB = q0 + 16 + l16; if (rqB > S_ - 1) rqB = S_ - 1;
    const bf16x8 aqA0 = load8(Qh + rqA * DH_ + quad * 8);
    const bf16x8 aqA1 = load8(Qh + rqA * DH_ + 32 + quad * 8);
    const bf16x8 aqB0 = load8(Qh + rqB * DH_ + quad * 8);
    const bf16x8 aqB1 = load8(Qh + rqB * DH_ + 32 + quad * 8);

    const int g0 = ((l16 >> 2) << 3) + (l16 & 3);   // permuted K row (zero-shuffle)
    const int g1 = g0 + 4;

    f32x4 oA[4] = {}, oB[4] = {};
    float lpA = 0.f, lpB = 0.f;

    bf16x8 ka[4], kb_[4];
    {
        int r0 = g0; if (r0 > S_ - 1) r0 = S_ - 1;
        int r1 = g1; if (r1 > S_ - 1) r1 = S_ - 1;
        ka[0] = load8(Kh + r0 * DH_ + quad * 8);
        ka[1] = load8(Kh + r0 * DH_ + 32 + quad * 8);
        ka[2] = load8(Kh + r1 * DH_ + quad * 8);
        ka[3] = load8(Kh + r1 * DH_ + 32 + quad * 8);
    }

    auto body = [&](bf16x8 (&KC)[4], bf16x8 (&KN)[4], const int j0, const bool pf) {
        bf16x8 v0 = load8(Vh + (l16)      * SP + j0 + quad * 8);
        bf16x8 v1 = load8(Vh + (16 + l16) * SP + j0 + quad * 8);
        bf16x8 v2 = load8(Vh + (32 + l16) * SP + j0 + quad * 8);
        bf16x8 v3 = load8(Vh + (48 + l16) * SP + j0 + quad * 8);
        if (pf) {
            int r0 = j0 + 32 + g0; if (r0 > S_ - 1) r0 = S_ - 1;
            int r1 = j0 + 32 + g1; if (r1 > S_ - 1) r1 = S_ - 1;
            KN[0] = load8(Kh + r0 * DH_ + quad * 8);
            KN[1] = load8(Kh + r0 * DH_ + 32 + quad * 8);
            KN[2] = load8(Kh + r1 * DH_ + quad * 8);
            KN[3] = load8(Kh + r1 * DH_ + 32 + quad * 8);
        }
        f32x4 sA0 = {}, sA1 = {}, sB0 = {}, sB1 = {};
        __builtin_amdgcn_s_setprio(1);
        sA0 = MFMA_BF16(KC[0], aqA0, sA0, 0, 0, 0);
        sA0 = MFMA_BF16(KC[1], aqA1, sA0, 0, 0, 0);
        sA1 = MFMA_BF16(KC[2], aqA0, sA1, 0, 0, 0);
        sA1 = MFMA_BF16(KC[3], aqA1, sA1, 0, 0, 0);
        sB0 = MFMA_BF16(KC[0], aqB0, sB0, 0, 0, 0);
        sB0 = MFMA_BF16(KC[1], aqB1, sB0, 0, 0, 0);
        sB1 = MFMA_BF16(KC[2], aqB0, sB1, 0, 0, 0);
        sB1 = MFMA_BF16(KC[3], aqB1, sB1, 0, 0, 0);
        __builtin_amdgcn_s_setprio(0);

        const f32x4 mk0 = *reinterpret_cast<const f32x4*>(&smask[j0 + quad * 8]);
        const f32x4 mk1 = *reinterpret_cast<const f32x4*>(&smask[j0 + quad * 8 + 4]);
        bf16x8 apA, apB;
#pragma unroll
        for (int r = 0; r < 4; ++r) {
            const int c0 = j0 + quad * 8 + r;
            const int c1 = c0 + 4;
            const float eA0 = (c0 < S_) ? __expf(sA0[r] * mk0[r]) : 0.f;
            const float eA1 = (c1 < S_) ? __expf(sA1[r] * mk1[r]) : 0.f;
            const float eB0 = (c0 < S_) ? __expf(sB0[r] * mk0[r]) : 0.f;
            const float eB1 = (c1 < S_) ? __expf(sB1[r] * mk1[r]) : 0.f;
            lpA += eA0 + eA1;               // P=0 on pad cols kills V poison
            lpB += eB0 + eB1;
            apA[r] = (bf16_t)eA0; apA[r + 4] = (bf16_t)eA1;
            apB[r] = (bf16_t)eB0; apB[r + 4] = (bf16_t)eB1;
        }
        __builtin_amdgcn_s_setprio(1);
        oA[0] = MFMA_BF16(apA, v0, oA[0], 0, 0, 0);
        oB[0] = MFMA_BF16(apB, v0, oB[0], 0, 0, 0);
        oA[1] = MFMA_BF16(apA, v1, oA[1], 0, 0, 0);
        oB[1] = MFMA_BF16(apB, v1, oB[1], 0, 0, 0);
        oA[2] = MFMA_BF16(apA, v2, oA[2], 0, 0, 0);
        oB[2] = MFMA_BF16(apB, v2, oB[2], 0, 0, 0);
        oA[3] = MFMA_BF16(apA, v3, oA[3], 0, 0, 0);
        oB[3] = MFMA_BF16(apB, v3, oB[3], 0, 0, 0);
        __builtin_amdgcn_s_setprio(0);
    };

    for (int j0 = 0; j0 < S_; j0 += 64) {           // 19 bodies, ka/kb alternate
        body(ka, kb_, j0, j0 + 32 < S_);
        if (j0 + 32 < S_) body(kb_, ka, j0 + 32, j0 + 64 < S_);
    }

    float lsA = lpA, lsB = lpB;
    lsA += __shfl_xor(lsA, 16); lsA += __shfl_xor(lsA, 32);
    lsB += __shfl_xor(lsB, 16); lsB += __shfl_xor(lsB, 32);
    float livA[4], livB[4];
#pragma unroll
    for (int r = 0; r < 4; ++r) {
        livA[r] = 1.0f / __shfl(lsA, quad * 4 + r); // lanes 0..15 hold full sums
        livB[r] = 1.0f / __shfl(lsB, quad * 4 + r);
    }

#pragma unroll
    for (int t = 0; t < 4; ++t) {
#pragma unroll
        for (int r = 0; r < 4; ++r) {
            const int sA = q0 + quad * 4 + r;
            const int sB = sA + 16;
            if (sA < S_)
                Ctx[((size_t)(b * S_ + sA) * NH_ + h) * DH_ + t * 16 + l16] =
                    (bf16_t)(oA[t][r] * livA[r]);
            if (sB < S_)
                Ctx[((size_t)(b * S_ + sB) * NH_ + h) * DH_ + t * 16 + l16] =
                    (bf16_t)(oB[t][r] * livB[r]);
        }
    }
}

// ---------------- output projection (R9 1-phase, known-good) ----------------
// 1-D grid 1160 = 145 m-tiles x 8 n-tiles, slab-swizzled.
__global__ __launch_bounds__(256) void out_gemm(
    const bf16_t* __restrict__ Ctx, const bf16_t* __restrict__ Wob,
    const float* __restrict__ bo, float* __restrict__ Out)
{
    __shared__ bf16_t smem[8192];
    bf16_t* sA = smem;
    bf16_t* sB = smem + 4096;
    const int tid  = threadIdx.x;
    const int w    = tid >> 6, lane = tid & 63;
    const int quad = lane >> 4, l16 = lane & 15;
    const int wm = w & 1, wn = w >> 1;

    const int t    = (blockIdx.x & 7) * 145 + (blockIdx.x >> 3);  // 1160%8==0
    const int slab = t / 64;                                      // 8 m x 8 n = 64
    const int rem  = t - slab * 64;
    int mt, nt;
    if (slab < 18) { nt = rem >> 3; mt = slab * 8 + (rem & 7); }
    else           { nt = rem;      mt = 144; }
    const int m0 = mt * 128, n0 = nt * 128;

    const int f0 = tid, f1 = 256 + tid;
    const int rA0 = f0 >> 2, cA0 = (f0 & 3) * 8;
    const int rA1 = f1 >> 2, cA1 = (f1 & 3) * 8;
    int ga0 = m0 + rA0; if (ga0 > M_ - 1) ga0 = M_ - 1;
    int ga1 = m0 + rA1; if (ga1 > M_ - 1) ga1 = M_ - 1;
    const bf16_t* pA0 = Ctx + (size_t)ga0 * H_ + cA0;
    const bf16_t* pA1 = Ctx + (size_t)ga1 * H_ + cA1;
    const bf16_t* pB0 = Wob + (size_t)(n0 + rA0) * H_ + cA0;
    const bf16_t* pB1 = Wob + (size_t)(n0 + rA1) * H_ + cA1;
    bf16_t* lA0 = sA + w * 512;
    bf16_t* lA1 = sA + 2048 + w * 512;
    bf16_t* lB0 = sB + w * 512;
    bf16_t* lB1 = sB + 2048 + w * 512;

    f32x4 acc[4][4] = {};
    for (int k0 = 0; k0 < H_; k0 += 32) {
        STAGE16(pA0 + k0, lA0);
        STAGE16(pA1 + k0, lA1);
        STAGE16(pB0 + k0, lB0);
        STAGE16(pB1 + k0, lB1);
        __syncthreads();
        bf16x8 af[4], bfv[4];
#pragma unroll
        for (int tt = 0; tt < 4; ++tt) {
            af[tt]  = load8(sA + (wm * 64 + tt * 16 + l16) * 32 + quad * 8);
            bfv[tt] = load8(sB + (wn * 64 + tt * 16 + l16) * 32 + quad * 8);
        }
#pragma unroll
        for (int i = 0; i < 4; ++i)
#pragma unroll
            for (int j = 0; j < 4; ++j)
                acc[i][j] = MFMA_BF16(bfv[j], af[i], acc[i][j], 0, 0, 0);  // swapped
        __syncthreads();
    }

    // swapped: m = m0+wm*64+i*16+l16, n-run = n0+wn*64+j*16+quad*4+{0..3}
#pragma unroll
    for (int j = 0; j < 4; ++j) {
        const int nb = n0 + wn * 64 + j * 16 + quad * 4;
        const f32x4 b4 = *reinterpret_cast<const f32x4*>(&bo[nb]);
#pragma unroll
        for (int i = 0; i < 4; ++i) {
            const int m = m0 + wm * 64 + i * 16 + l16;
            if (m >= M_) continue;
            f32x4 v = acc[i][j] + b4;
            *reinterpret_cast<f32x4*>(Out + (size_t)m * H_ + nb) = v;
        }
    }
}

extern "C" void kernel_launch(void* const* d_in, const int* in_sizes, int n_in,
                              void* d_out, int out_size, void* d_ws, size_t ws_size,
                              hipStream_t stream) {
    const float* hidden = (const float*)d_in[0];
    const float* mask   = (const float*)d_in[1];
    const float* Wq = (const float*)d_in[2];
    const float* bq = (const float*)d_in[3];
    const float* Wk = (const float*)d_in[4];
    const float* bk = (const float*)d_in[5];
    const float* Wv = (const float*)d_in[6];
    const float* bv = (const float*)d_in[7];
    const float* Wo = (const float*)d_in[8];
    const float* bo = (const float*)d_in[9];
    float* out = (float*)d_out;

    const size_t QK_EL = (size_t)B_ * NH_ * S_ * DH_;   // 18,907,136
    const size_t VT_EL = (size_t)B_ * NH_ * SP * DH_;   // 19,922,944
    const size_t X_EL  = (size_t)M_ * H_;               // 18,907,136
    const size_t W_EL  = (size_t)H_ * H_;               // 1,048,576
    const size_t NEED  = (2 * QK_EL + VT_EL + X_EL + 4 * W_EL) * sizeof(bf16_t); // ~161.7 MB
    if (ws_size < NEED) {
        hipMemsetAsync(d_out, 0, (size_t)out_size * sizeof(float), stream);
        return;
    }

    bf16_t* ws    = (bf16_t*)d_ws;
    bf16_t* Qb    = ws;
    bf16_t* Kb    = Qb + QK_EL;
    bf16_t* VTb   = Kb + QK_EL;
    bf16_t* XbCtx = VTb + VT_EL;      // X_bf16 during qkv; Ctx afterwards
    bf16_t* Wqb   = XbCtx + X_EL;
    bf16_t* Wkb   = Wqb + W_EL;
    bf16_t* Wvb   = Wkb + W_EL;
    bf16_t* Wob   = Wvb + W_EL;

    cvt_f32_bf16<<<2048, 256, 0, stream>>>(hidden, XbCtx, (int)(X_EL / 8));
    cvt_w4<<<2048, 256, 0, stream>>>(Wq, Wk, Wv, Wo, Wqb);   // Wqb..Wob contiguous

    qkv_gemm<<<dim3(876), dim3(512), 0, stream>>>(XbCtx, Wqb, Wkb, Wvb, bq, bk, bv, Qb, Kb, VTb);

    flash_attn<<<dim3(2560), dim3(256), 0, stream>>>(Qb, Kb, VTb, mask, XbCtx);  // Ctx aliases Xb

    out_gemm<<<dim3(1160), dim3(256), 0, stream>>>(XbCtx, Wob, bo, out);
}

// Round 8
// 470.053 us; speedup vs baseline: 1.0953x; 1.0953x over previous
//
#include <hip/hip_runtime.h>
#include <hip/hip_bf16.h>

// B=32, S=577, H=1024, NH=16, DH=64. fp32 inputs / fp32 OUTPUT.
// Round 14: (1) qkv_gemm REVERTED to R9 1-phase 128^2 (best measured: 180us,
// 645 TF; R12/R13 8-phase ports were 0/-10% — conflicts proved to be DMA-
// write-side, not read-side, so the swizzle lever was void on this shape).
// (2) flash_attn: 4 q-tiles (64 rows) per wave — K/V loads shared by 4 score
// tiles: 8 loads now feed 32 MFMA (was 16), net ~1.75x fewer loads per FLOP.
// 2 waves/SIMD (launch_bounds 256,2), grid 1536 XCD-chunked (64 bh/XCD).
// (3) cvt kernels merged into one launch. out_gemm R9 (known-good).

typedef __bf16 bf16_t;
typedef __bf16 bf16x8 __attribute__((ext_vector_type(8)));
typedef __bf16 bf16x4 __attribute__((ext_vector_type(4)));
typedef float f32x4 __attribute__((ext_vector_type(4)));

#define B_   32
#define S_   577
#define SP   608
#define H_   1024
#define NH_  16
#define DH_  64
#define M_   (B_ * S_)    // 18464

typedef __attribute__((address_space(3))) unsigned int lds_u32;
typedef const __attribute__((address_space(1))) unsigned int glb_u32;
#define STAGE16(gp, lp) __builtin_amdgcn_global_load_lds((glb_u32*)(gp), (lds_u32*)(lp), 16, 0, 0)
#define MFMA_BF16 __builtin_amdgcn_mfma_f32_16x16x32_bf16

__device__ __forceinline__ bf16x8 load8(const bf16_t* p) {
    return *reinterpret_cast<const bf16x8*>(p);
}
__device__ __forceinline__ bf16x8 load8f(const float* p) {
    f32x4 a = *reinterpret_cast<const f32x4*>(p);
    f32x4 b = *reinterpret_cast<const f32x4*>(p + 4);
    bf16x8 r;
    r[0] = (bf16_t)a[0]; r[1] = (bf16_t)a[1]; r[2] = (bf16_t)a[2]; r[3] = (bf16_t)a[3];
    r[4] = (bf16_t)b[0]; r[5] = (bf16_t)b[1]; r[6] = (bf16_t)b[2]; r[7] = (bf16_t)b[3];
    return r;
}

// ---------------- fused fp32 -> bf16 convert (X + 4 weights, one launch) ----
__global__ __launch_bounds__(256) void cvt_all(
    const float* __restrict__ x,
    const float* __restrict__ w0, const float* __restrict__ w1,
    const float* __restrict__ w2, const float* __restrict__ w3,
    bf16_t* __restrict__ xdst, bf16_t* __restrict__ wdst, int xn8)
{
    int i = blockIdx.x * blockDim.x + threadIdx.x;
    const int stride = gridDim.x * blockDim.x;
    const int total = xn8 + 4 * (1 << 17);
    for (; i < total; i += stride) {
        if (i < xn8) {
            *reinterpret_cast<bf16x8*>(xdst + (size_t)i * 8) = load8f(x + (size_t)i * 8);
        } else {
            const int j = i - xn8;
            const int which = j >> 17, off = j & ((1 << 17) - 1);
            const float* s = (which == 0) ? w0 : (which == 1) ? w1 : (which == 2) ? w2 : w3;
            *reinterpret_cast<bf16x8*>(wdst + (size_t)j * 8) = load8f(s + (size_t)off * 8);
        }
    }
}

// ---- R9 1-phase m97 main loop (best measured for this shape) ----
#define GEMM_MAINLOOP(SWAP)                                                      \
    for (int k0 = 0; k0 < H_; k0 += 32) {                                        \
        STAGE16(pA0 + k0, lA0);                                                  \
        STAGE16(pA1 + k0, lA1);                                                  \
        STAGE16(pB0 + k0, lB0);                                                  \
        STAGE16(pB1 + k0, lB1);                                                  \
        __syncthreads();                                                         \
        bf16x8 af[4], bfv[4];                                                    \
        _Pragma("unroll")                                                        \
        for (int tt = 0; tt < 4; ++tt) {                                         \
            af[tt]  = load8(sA + (wm * 64 + tt * 16 + l16) * 32 + quad * 8);     \
            bfv[tt] = load8(sB + (wn * 64 + tt * 16 + l16) * 32 + quad * 8);     \
        }                                                                        \
        _Pragma("unroll")                                                        \
        for (int i = 0; i < 4; ++i)                                              \
            _Pragma("unroll")                                                    \
            for (int j = 0; j < 4; ++j)                                          \
                acc[i][j] = (SWAP)                                               \
                    ? MFMA_BF16(bfv[j], af[i], acc[i][j], 0, 0, 0)               \
                    : MFMA_BF16(af[i], bfv[j], acc[i][j], 0, 0, 0);              \
        __syncthreads();                                                         \
    }

// ---------------- fused QKV projection (R9) ----------------
// 1-D grid 3480 = 145 m-tiles x 24 n-tiles; 8-m-tile slabs n-fast, XCD-chunked.
__global__ __launch_bounds__(256) void qkv_gemm(
    const bf16_t* __restrict__ Xb,
    const bf16_t* __restrict__ Wqb, const bf16_t* __restrict__ Wkb, const bf16_t* __restrict__ Wvb,
    const float* __restrict__ bq, const float* __restrict__ bk, const float* __restrict__ bv,
    bf16_t* __restrict__ Qb, bf16_t* __restrict__ Kb, bf16_t* __restrict__ VTb)
{
    __shared__ bf16_t smem[8192];          // A[128][32] | B[128][32], contiguous
    bf16_t* sA = smem;
    bf16_t* sB = smem + 4096;
    const int tid  = threadIdx.x;
    const int w    = tid >> 6, lane = tid & 63;
    const int quad = lane >> 4, l16 = lane & 15;
    const int wm = w & 1, wn = w >> 1;

    const int t    = (blockIdx.x & 7) * 435 + (blockIdx.x >> 3);  // bijective, 3480%8==0
    const int slab = t / 192;                                     // 8 m-tiles x 24 n = 192
    const int rem  = t - slab * 192;
    int mt, nt;
    if (slab < 18) { nt = rem >> 3; mt = slab * 8 + (rem & 7); }
    else           { nt = rem;      mt = 144; }                   // last partial slab
    const int m0 = mt * 128, n0 = nt * 128;

    const int which = n0 >> 10;            // 128-tile never straddles a weight boundary
    const int nrel0 = n0 & 1023;
    const bf16_t* Wb   = (which == 0) ? Wqb : (which == 1) ? Wkb : Wvb;
    const float*  bias = (which == 0) ? bq  : (which == 1) ? bk  : bv;
    const float   oscale = (which == 0) ? 0.125f : 1.0f;

    const int f0 = tid, f1 = 256 + tid;
    const int rA0 = f0 >> 2, cA0 = (f0 & 3) * 8;
    const int rA1 = f1 >> 2, cA1 = (f1 & 3) * 8;
    int ga0 = m0 + rA0; if (ga0 > M_ - 1) ga0 = M_ - 1;
    int ga1 = m0 + rA1; if (ga1 > M_ - 1) ga1 = M_ - 1;
    const bf16_t* pA0 = Xb + (size_t)ga0 * H_ + cA0;
    const bf16_t* pA1 = Xb + (size_t)ga1 * H_ + cA1;
    const bf16_t* pB0 = Wb + (size_t)(nrel0 + rA0) * H_ + cA0;
    const bf16_t* pB1 = Wb + (size_t)(nrel0 + rA1) * H_ + cA1;
    bf16_t* lA0 = sA + w * 512;            // wave-uniform bases (+lane*16B by HW)
    bf16_t* lA1 = sA + 2048 + w * 512;
    bf16_t* lB0 = sB + w * 512;
    bf16_t* lB1 = sB + 2048 + w * 512;

    f32x4 acc[4][4] = {};
    if (which != 2) {
        GEMM_MAINLOOP(1)
        // swapped: m = m0+wm*64+i*16+l16, n-run = 16*(wn*4+j)+quad*4+r
        bf16_t* QKout = (which == 0) ? Qb : Kb;
#pragma unroll
        for (int j = 0; j < 4; ++j) {
            const int u  = wn * 4 + j;                 // 16-col unit
            const int h  = (nrel0 >> 6) + (u >> 2);
            const int d0 = (u & 3) * 16 + quad * 4;
            const f32x4 b4 = *reinterpret_cast<const f32x4*>(&bias[nrel0 + u * 16 + quad * 4]);
#pragma unroll
            for (int i = 0; i < 4; ++i) {
                const int m = m0 + wm * 64 + i * 16 + l16;
                if (m >= M_) continue;
                const int b = m / S_, s = m - b * S_;
                const int bh = b * NH_ + h;
                bf16x4 pk;
#pragma unroll
                for (int r = 0; r < 4; ++r) pk[r] = (bf16_t)((acc[i][j][r] + b4[r]) * oscale);
                *reinterpret_cast<bf16x4*>(QKout + ((size_t)bh * S_ + s) * DH_ + d0) = pk;
            }
        }
    } else {
        GEMM_MAINLOOP(0)
        // normal: d from l16, s-run = m0+wm*64+i*16+quad*4+r
#pragma unroll
        for (int j = 0; j < 4; ++j) {
            const int nrel = nrel0 + wn * 64 + j * 16 + l16;
            const float bv_ = bias[nrel];
            const int h = nrel >> 6, d = nrel & 63;
#pragma unroll
            for (int i = 0; i < 4; ++i) {
                const int m = m0 + wm * 64 + i * 16 + quad * 4;
                const int b = m / S_, s = m - b * S_;
                if (m + 3 < M_ && s <= S_ - 4) {       // 4-run stays in one batch row
                    bf16x4 pk;
#pragma unroll
                    for (int r = 0; r < 4; ++r) pk[r] = (bf16_t)(acc[i][j][r] + bv_);
                    *reinterpret_cast<bf16x4*>(VTb + ((size_t)(b * NH_ + h) * DH_ + d) * SP + s) = pk;
                } else {
#pragma unroll
                    for (int r = 0; r < 4; ++r) {
                        const int mm = m + r;
                        if (mm >= M_) continue;
                        const int bb = mm / S_, ss = mm - bb * S_;
                        VTb[((size_t)(bb * NH_ + h) * DH_ + d) * SP + ss] = (bf16_t)(acc[i][j][r] + bv_);
                    }
                }
            }
        }
    }
}

// ---------------- flash attention: 4 q-tiles (64 rows) per wave ----------------
// grid 1536, block 256 (4 waves x 64 q-rows). XCD-chunked: 192 works/XCD,
// 3 blocks per bh, 64 bh/XCD exactly. Zero-shuffle swapped QK^T: lane
// (l16,quad) holds P[q][8*quad..8*quad+7] for each of its 4 q-tiles; K/V
// register fragments are SHARED across the 4 tiles (8 loads -> 32 MFMA).
__global__ __launch_bounds__(256, 2) void flash_attn(
    const bf16_t* __restrict__ Qb, const bf16_t* __restrict__ Kb,
    const bf16_t* __restrict__ VTb, const float* __restrict__ maskp,
    bf16_t* __restrict__ Ctx)
{
    __shared__ __align__(16) float smask[SP];       // 2432B, zero-padded tail
    const int tid  = threadIdx.x;
    const int w    = tid >> 6, lane = tid & 63;
    const int quad = lane >> 4, l16 = lane & 15;

    const int bid  = blockIdx.x;
    const int work = (bid & 7) * 192 + (bid >> 3);  // bijective (1536%8==0)
    const int bh   = work / 3;
    const int qx   = work - bh * 3;
    const int b    = bh >> 4, h = bh & 15;

    for (int i = tid; i < SP; i += 256)
        smask[i] = (i < S_) ? maskp[b * S_ + i] : 0.f;
    __syncthreads();

    int idx = qx * 4 + w; if (idx > 9) idx = 9;     // dup work, same values
    const int q0 = idx * 64;

    const bf16_t* Qh = Qb  + (size_t)bh * S_ * DH_;
    const bf16_t* Kh = Kb  + (size_t)bh * S_ * DH_;
    const bf16_t* Vh = VTb + (size_t)bh * DH_ * SP;

    bf16x8 aq[4][2];
#pragma unroll
    for (int t = 0; t < 4; ++t) {
        int rq = q0 + t * 16 + l16; if (rq > S_ - 1) rq = S_ - 1;
        aq[t][0] = load8(Qh + rq * DH_ + quad * 8);
        aq[t][1] = load8(Qh + rq * DH_ + 32 + quad * 8);
    }

    const int g0 = ((l16 >> 2) << 3) + (l16 & 3);   // permuted K row (zero-shuffle)
    const int g1 = g0 + 4;

    f32x4 o[4][4] = {};                              // [q-tile][d-block]
    float lp[4] = {0.f, 0.f, 0.f, 0.f};

    bf16x8 ka[4], kb_[4];
    {
        int r0 = g0; if (r0 > S_ - 1) r0 = S_ - 1;
        int r1 = g1; if (r1 > S_ - 1) r1 = S_ - 1;
        ka[0] = load8(Kh + r0 * DH_ + quad * 8);
        ka[1] = load8(Kh + r0 * DH_ + 32 + quad * 8);
        ka[2] = load8(Kh + r1 * DH_ + quad * 8);
        ka[3] = load8(Kh + r1 * DH_ + 32 + quad * 8);
    }

    auto body = [&](bf16x8 (&KC)[4], bf16x8 (&KN)[4], const int j0, const bool pf) {
        // V for this tile + K for next: issue before the compute chain.
        bf16x8 v0 = load8(Vh + (l16)      * SP + j0 + quad * 8);
        bf16x8 v1 = load8(Vh + (16 + l16) * SP + j0 + quad * 8);
        bf16x8 v2 = load8(Vh + (32 + l16) * SP + j0 + quad * 8);
        bf16x8 v3 = load8(Vh + (48 + l16) * SP + j0 + quad * 8);
        if (pf) {
            int r0 = j0 + 32 + g0; if (r0 > S_ - 1) r0 = S_ - 1;
            int r1 = j0 + 32 + g1; if (r1 > S_ - 1) r1 = S_ - 1;
            KN[0] = load8(Kh + r0 * DH_ + quad * 8);
            KN[1] = load8(Kh + r0 * DH_ + 32 + quad * 8);
            KN[2] = load8(Kh + r1 * DH_ + quad * 8);
            KN[3] = load8(Kh + r1 * DH_ + 32 + quad * 8);
        }
        // scores for 4 q-tiles sharing KC: s0[t][r]=S[q][j0+8q+r], s1: +4
        f32x4 s0[4], s1[4];
        __builtin_amdgcn_s_setprio(1);
#pragma unroll
        for (int t = 0; t < 4; ++t) {
            f32x4 z0 = {}, z1 = {};
            z0 = MFMA_BF16(KC[0], aq[t][0], z0, 0, 0, 0);
            z0 = MFMA_BF16(KC[1], aq[t][1], z0, 0, 0, 0);
            z1 = MFMA_BF16(KC[2], aq[t][0], z1, 0, 0, 0);
            z1 = MFMA_BF16(KC[3], aq[t][1], z1, 0, 0, 0);
            s0[t] = z0; s1[t] = z1;
        }
        __builtin_amdgcn_s_setprio(0);

        const f32x4 mk0 = *reinterpret_cast<const f32x4*>(&smask[j0 + quad * 8]);
        const f32x4 mk1 = *reinterpret_cast<const f32x4*>(&smask[j0 + quad * 8 + 4]);
        bf16x8 ap[4];
#pragma unroll
        for (int t = 0; t < 4; ++t) {
#pragma unroll
            for (int r = 0; r < 4; ++r) {
                const int c0 = j0 + quad * 8 + r;
                const int c1 = c0 + 4;
                const float e0 = (c0 < S_) ? __expf(s0[t][r] * mk0[r]) : 0.f;
                const float e1 = (c1 < S_) ? __expf(s1[t][r] * mk1[r]) : 0.f;
                lp[t] += e0 + e1;           // P=0 on pad cols kills V poison
                ap[t][r] = (bf16_t)e0; ap[t][r + 4] = (bf16_t)e1;
            }
        }
        __builtin_amdgcn_s_setprio(1);
#pragma unroll
        for (int t = 0; t < 4; ++t) {
            o[t][0] = MFMA_BF16(ap[t], v0, o[t][0], 0, 0, 0);
            o[t][1] = MFMA_BF16(ap[t], v1, o[t][1], 0, 0, 0);
            o[t][2] = MFMA_BF16(ap[t], v2, o[t][2], 0, 0, 0);
            o[t][3] = MFMA_BF16(ap[t], v3, o[t][3], 0, 0, 0);
        }
        __builtin_amdgcn_s_setprio(0);
    };

    for (int j0 = 0; j0 < S_; j0 += 64) {           // 19 bodies, ka/kb alternate
        body(ka, kb_, j0, j0 + 32 < S_);
        if (j0 + 32 < S_) body(kb_, ka, j0 + 32, j0 + 64 < S_);
    }

    // row sums: quads hold disjoint k-slices of row q=l16 -> reduce over quads
    float liv[4][4];
#pragma unroll
    for (int t = 0; t < 4; ++t) {
        float ls = lp[t];
        ls += __shfl_xor(ls, 16); ls += __shfl_xor(ls, 32);
#pragma unroll
        for (int r = 0; r < 4; ++r)
            liv[t][r] = 1.0f / __shfl(ls, quad * 4 + r);   // lanes 0..15 full sums
    }

#pragma unroll
    for (int t = 0; t < 4; ++t) {
#pragma unroll
        for (int dt = 0; dt < 4; ++dt) {
#pragma unroll
            for (int r = 0; r < 4; ++r) {
                const int s = q0 + t * 16 + quad * 4 + r;
                if (s < S_)
                    Ctx[((size_t)(b * S_ + s) * NH_ + h) * DH_ + dt * 16 + l16] =
                        (bf16_t)(o[t][dt][r] * liv[t][r]);
            }
        }
    }
}

// ---------------- output projection (R9 1-phase, known-good) ----------------
// 1-D grid 1160 = 145 m-tiles x 8 n-tiles, slab-swizzled.
__global__ __launch_bounds__(256) void out_gemm(
    const bf16_t* __restrict__ Ctx, const bf16_t* __restrict__ Wob,
    const float* __restrict__ bo, float* __restrict__ Out)
{
    __shared__ bf16_t smem[8192];
    bf16_t* sA = smem;
    bf16_t* sB = smem + 4096;
    const int tid  = threadIdx.x;
    const int w    = tid >> 6, lane = tid & 63;
    const int quad = lane >> 4, l16 = lane & 15;
    const int wm = w & 1, wn = w >> 1;

    const int t    = (blockIdx.x & 7) * 145 + (blockIdx.x >> 3);  // 1160%8==0
    const int slab = t / 64;                                      // 8 m x 8 n = 64
    const int rem  = t - slab * 64;
    int mt, nt;
    if (slab < 18) { nt = rem >> 3; mt = slab * 8 + (rem & 7); }
    else           { nt = rem;      mt = 144; }
    const int m0 = mt * 128, n0 = nt * 128;

    const int f0 = tid, f1 = 256 + tid;
    const int rA0 = f0 >> 2, cA0 = (f0 & 3) * 8;
    const int rA1 = f1 >> 2, cA1 = (f1 & 3) * 8;
    int ga0 = m0 + rA0; if (ga0 > M_ - 1) ga0 = M_ - 1;
    int ga1 = m0 + rA1; if (ga1 > M_ - 1) ga1 = M_ - 1;
    const bf16_t* pA0 = Ctx + (size_t)ga0 * H_ + cA0;
    const bf16_t* pA1 = Ctx + (size_t)ga1 * H_ + cA1;
    const bf16_t* pB0 = Wob + (size_t)(n0 + rA0) * H_ + cA0;
    const bf16_t* pB1 = Wob + (size_t)(n0 + rA1) * H_ + cA1;
    bf16_t* lA0 = sA + w * 512;
    bf16_t* lA1 = sA + 2048 + w * 512;
    bf16_t* lB0 = sB + w * 512;
    bf16_t* lB1 = sB + 2048 + w * 512;

    f32x4 acc[4][4] = {};
    GEMM_MAINLOOP(1)

    // swapped: m = m0+wm*64+i*16+l16, n-run = n0+wn*64+j*16+quad*4+{0..3}
#pragma unroll
    for (int j = 0; j < 4; ++j) {
        const int nb = n0 + wn * 64 + j * 16 + quad * 4;
        const f32x4 b4 = *reinterpret_cast<const f32x4*>(&bo[nb]);
#pragma unroll
        for (int i = 0; i < 4; ++i) {
            const int m = m0 + wm * 64 + i * 16 + l16;
            if (m >= M_) continue;
            f32x4 v = acc[i][j] + b4;
            *reinterpret_cast<f32x4*>(Out + (size_t)m * H_ + nb) = v;
        }
    }
}

extern "C" void kernel_launch(void* const* d_in, const int* in_sizes, int n_in,
                              void* d_out, int out_size, void* d_ws, size_t ws_size,
                              hipStream_t stream) {
    const float* hidden = (const float*)d_in[0];
    const float* mask   = (const float*)d_in[1];
    const float* Wq = (const float*)d_in[2];
    const float* bq = (const float*)d_in[3];
    const float* Wk = (const float*)d_in[4];
    const float* bk = (const float*)d_in[5];
    const float* Wv = (const float*)d_in[6];
    const float* bv = (const float*)d_in[7];
    const float* Wo = (const float*)d_in[8];
    const float* bo = (const float*)d_in[9];
    float* out = (float*)d_out;

    const size_t QK_EL = (size_t)B_ * NH_ * S_ * DH_;   // 18,907,136
    const size_t VT_EL = (size_t)B_ * NH_ * SP * DH_;   // 19,922,944
    const size_t X_EL  = (size_t)M_ * H_;               // 18,907,136
    const size_t W_EL  = (size_t)H_ * H_;               // 1,048,576
    const size_t NEED  = (2 * QK_EL + VT_EL + X_EL + 4 * W_EL) * sizeof(bf16_t); // ~161.7 MB
    if (ws_size < NEED) {
        hipMemsetAsync(d_out, 0, (size_t)out_size * sizeof(float), stream);
        return;
    }

    bf16_t* ws    = (bf16_t*)d_ws;
    bf16_t* Qb    = ws;
    bf16_t* Kb    = Qb + QK_EL;
    bf16_t* VTb   = Kb + QK_EL;
    bf16_t* XbCtx = VTb + VT_EL;      // X_bf16 during qkv; Ctx afterwards
    bf16_t* Wqb   = XbCtx + X_EL;
    bf16_t* Wkb   = Wqb + W_EL;
    bf16_t* Wvb   = Wkb + W_EL;
    bf16_t* Wob   = Wvb + W_EL;

    cvt_all<<<2048, 256, 0, stream>>>(hidden, Wq, Wk, Wv, Wo, XbCtx, Wqb, (int)(X_EL / 8));

    qkv_gemm<<<dim3(3480), dim3(256), 0, stream>>>(XbCtx, Wqb, Wkb, Wvb, bq, bk, bv, Qb, Kb, VTb);

    flash_attn<<<dim3(1536), dim3(256), 0, stream>>>(Qb, Kb, VTb, mask, XbCtx);  // Ctx aliases Xb

    out_gemm<<<dim3(1160), dim3(256), 0, stream>>>(XbCtx, Wob, bo, out);
}